// Round 6
// baseline (399.247 us; speedup 1.0000x reference)
//
#include <hip/hip_runtime.h>
#include <math.h>

// SpinSphericalBlock: separable spin-weighted SHT -> channel mix -> inverse SHT
// -> complex BN (spin0 mean, via Parseval on G) -> magnitude-ReLU gating.
//
// Constants: B=8, RES=64, RES_OUT=32, L=15, SPINS_IN=(0,1), SPINS_OUT=(0,1,2),
// C_IN=64, C_OUT=128, NM=31. Output: out_size=3,145,728 float32 = Re(y),
// (b,t,p,s,d) row-major (established R0-R4).
//
// R6 pipeline (fmap never materialized):
//   K0 k_tables:     Wigner/twiddle tables (fp64) + zero stats accumulators
//   K1 k_phi_in:     F[bt,m,iu]    = sum_p x[bt,p,iu] e^{-im phi_p}
//   K2 k_theta_in:   coeffs[b,k,iu]= sum_t A_in[i,k,t] F[b,t,m(k),iu]
//   K3 k_mix:        oc[b,k,sd]    = sum_iu coeffs * kernel[l(k),i,s,u,d]
//   K4 k_theta_out:  G[bt,m,sd]    = sum_l A_out[s,k,t] oc[b,k,sd]
//                    + atomic stats: ssq += sum|G|^2 ; m==0: ssr,ssi += sum G
//                    (DFT orthogonality: mean = ssr/256, E|y|^2 = ssq/256)
//   K5 k_synth_final: y = BN(sum_m G e^{+im phi'_p}) -> gate -> write Re(y)

#define PI_D 3.14159265358979323846

// ---------------- workspace layout (bytes) ----------------
#define OFF_TW_IN   ((size_t)0)         // 31*64 float2      = 15872
#define OFF_TW_OUT  ((size_t)16128)     // 31*32 float2      = 7936
#define OFF_A_IN    ((size_t)24320)     // 2*256*64 float    = 131072
#define OFF_A_OUT   ((size_t)155648)    // 3*256*32 float    = 98304
#define OFF_STATS   ((size_t)254208)    // 3*384 float       = 4608
#define OFF_R1      ((size_t)260608)    // F (16.25MB) then oc (6.3MB)
#define OFF_R2      ((size_t)25426688)  // coeffs (2.1MB) then G (24.4MB)
// total ~49.8 MB (known good from R5)

__device__ inline int isqrt_k(int k) {
    int l = (int)sqrtf((float)k + 0.5f);
    while (l * l > k) --l;
    while ((l + 1) * (l + 1) <= k) ++l;
    return l;
}

// d^l_{m,n}(theta), exact factorial-sum formula, double precision.
__device__ double wigner_d_dev(int l, int m, int n, double theta, const double* lf) {
    int an = n < 0 ? -n : n;
    int am = m < 0 ? -m : m;
    if (l < an || l < am) return 0.0;
    double cb = cos(0.5 * theta), sb = sin(0.5 * theta);
    double pref = 0.5 * (lf[l + m] + lf[l - m] + lf[l + n] + lf[l - n]);
    int kmin = max(0, n - m), kmax = min(l + n, l - m);
    if (kmax < kmin) return 0.0;
    double p = pow(cb, (double)(2 * l + n - m - 2 * kmin)) * pow(sb, (double)(m - n + 2 * kmin));
    double r = (sb * sb) / (cb * cb);
    double acc = 0.0;
    for (int k = kmin; k <= kmax; ++k) {
        double lg = pref - (lf[l + n - k] + lf[k] + lf[m - n + k] + lf[l - m - k]);
        double term = exp(lg) * p;
        acc += ((m - n + k) & 1) ? -term : term;
        p *= r;
    }
    return acc;
}

// K0: tables + zero the stats accumulators.
// ranges: tw_in 1984 | tw_out 992 | A_in 32768 | A_out 24576 | stats 1152
__global__ __launch_bounds__(256) void k_tables(float2* __restrict__ tw_in,
                                                float2* __restrict__ tw_out,
                                                float* __restrict__ A_in,
                                                float* __restrict__ A_out,
                                                float* __restrict__ stats) {
    __shared__ double lf[40];
    if (threadIdx.x == 0) {
        lf[0] = 0.0;
        for (int j = 1; j < 40; ++j) lf[j] = lf[j - 1] + log((double)j);
    }
    __syncthreads();
    int idx = blockIdx.x * 256 + threadIdx.x;
    if (idx < 1984) {  // tw_in[mi][p] = e^{-i m phi_p}, phi_p = 2pi p/64
        int mi = idx >> 6, p = idx & 63;
        int m = mi - 15;
        double ang = -(double)m * 2.0 * PI_D * (double)p / 64.0;
        tw_in[idx] = make_float2((float)cos(ang), (float)sin(ang));
        return;
    }
    idx -= 1984;
    if (idx < 992) {   // tw_out[mi][p] = e^{+i m phi'_p}, phi'_p = 2pi p/32
        int mi = idx >> 5, p = idx & 31;
        int m = mi - 15;
        double ang = (double)m * 2.0 * PI_D * (double)p / 32.0;
        tw_out[idx] = make_float2((float)cos(ang), (float)sin(ang));
        return;
    }
    idx -= 992;
    if (idx < 32768) { // A_in[i][k][t] = (-1)^m norm_l w_t d^l_{m,-s_i}(theta_t)
        int t = idx & 63, k = (idx >> 6) & 255, i = idx >> 14;
        int l = isqrt_k(k);
        int m = k - l * l - l;
        int n = -i;
        double theta = ((double)t + 0.5) * PI_D / 64.0;
        double w = sin(theta) * (PI_D / 64.0) * (2.0 * PI_D / 64.0);
        double norm = sqrt((2.0 * l + 1.0) / (4.0 * PI_D));
        double d = wigner_d_dev(l, m, n, theta, lf);
        A_in[idx] = (float)(((m & 1) ? -1.0 : 1.0) * norm * w * d);
        return;
    }
    idx -= 32768;
    if (idx < 24576) { // A_out[s][k][t] = (-1)^m norm_l d^l_{m,-s}(theta'_t)
        int t = idx & 31, k = (idx >> 5) & 255, s = idx >> 13;
        int l = isqrt_k(k);
        int m = k - l * l - l;
        int n = -s;
        double theta = ((double)t + 0.5) * PI_D / 32.0;
        double norm = sqrt((2.0 * l + 1.0) / (4.0 * PI_D));
        double d = wigner_d_dev(l, m, n, theta, lf);
        A_out[idx] = (float)(((m & 1) ? -1.0 : 1.0) * norm * d);
        return;
    }
    idx -= 24576;
    if (idx < 1152) stats[idx] = 0.f;  // ssr[384] | ssi[384] | ssq[384]
}

// K1: partial phi-DFT. grid 512 (bt), 256 threads: (iu 0..127, mh 0..1).
// Thread owns 16 m-accumulators (mh*16 .. mh*16+15, mi=31 guarded), reads its
// x column directly (wave-coalesced 256B), twiddles via wave-uniform L1 loads.
__global__ __launch_bounds__(256) void k_phi_in(const float* __restrict__ xr,
                                                const float* __restrict__ xi,
                                                const float2* __restrict__ tw_in,
                                                float2* __restrict__ F) {
    int bt = blockIdx.x;
    int iu = threadIdx.x & 127, mh = threadIdx.x >> 7;
    int mi0 = mh * 16;
    float2 acc[16];
#pragma unroll
    for (int j = 0; j < 16; ++j) acc[j] = make_float2(0.f, 0.f);
    const float* xrb = xr + (size_t)bt * 8192 + iu;
    const float* xib = xi + (size_t)bt * 8192 + iu;
    for (int p = 0; p < 64; ++p) {
        float a = xrb[(size_t)p * 128];
        float b = xib[(size_t)p * 128];
#pragma unroll
        for (int j = 0; j < 16; ++j) {
            int mi = mi0 + j;
            if (mi < 31) {
                float2 w = tw_in[mi * 64 + p];  // wave-uniform -> broadcast
                acc[j].x += a * w.x - b * w.y;
                acc[j].y += a * w.y + b * w.x;
            }
        }
    }
    float2* Fb = F + (size_t)bt * 31 * 128 + iu;
#pragma unroll
    for (int j = 0; j < 16; ++j) {
        int mi = mi0 + j;
        if (mi < 31) Fb[(size_t)mi * 128] = acc[j];
    }
}

// K2: theta contraction. grid (31, 8, 2) = (mi, b, parity), 128 threads (iu).
// Stages A_in rows for l = par+2j (zero-filled below |m|) in LDS; F read once.
__global__ __launch_bounds__(128) void k_theta_in(const float2* __restrict__ F,
                                                  const float* __restrict__ A_in,
                                                  float2* __restrict__ coeffs) {
    __shared__ float lds_A[2][8][64];  // 4KB
    int mi = blockIdx.x, b = blockIdx.y, par = blockIdx.z;
    int m = mi - 15;
    int am = m < 0 ? -m : m;
    int tid = threadIdx.x;
    for (int idx = tid; idx < 1024; idx += 128) {
        int i = idx >> 9, j = (idx >> 6) & 7, t = idx & 63;
        int l = par + 2 * j;
        float v = 0.f;
        if (l >= am) v = A_in[((size_t)i * 256 + (l * l + l + m)) * 64 + t];
        lds_A[i][j][t] = v;
    }
    __syncthreads();
    int iu = tid, i = iu >> 6;
    float2 acc[8];
#pragma unroll
    for (int j = 0; j < 8; ++j) acc[j] = make_float2(0.f, 0.f);
    const float2* Fb = F + ((size_t)b * 64 * 31 + mi) * 128 + iu;
    for (int t = 0; t < 64; ++t) {
        float2 f = Fb[(size_t)t * 31 * 128];
#pragma unroll
        for (int j = 0; j < 8; ++j) {
            float a = lds_A[i][j][t];   // wave-uniform -> broadcast
            acc[j].x += a * f.x;
            acc[j].y += a * f.y;
        }
    }
#pragma unroll
    for (int j = 0; j < 8; ++j) {
        int l = par + 2 * j;
        if (l >= am)
            coeffs[((size_t)b * 256 + (l * l + l + m)) * 128 + iu] = acc[j];
    }
}

// K3: channel mix. grid (16 l, 62 row-tiles), 192 threads (d-pairs).
// Thread computes 4 rows x 2 sd. coeffs via block-uniform (scalar) loads,
// kernel via float2 vector loads.
__global__ __launch_bounds__(192) void k_mix(const float2* __restrict__ coeffs,
                                             const float* __restrict__ kr,
                                             const float* __restrict__ ki,
                                             float2* __restrict__ oc) {
    int l = blockIdx.x;
    int nm = 2 * l + 1;
    int R = 8 * nm;
    int r0 = blockIdx.y * 4;
    if (r0 >= R) return;
    int tid = threadIdx.x;
    int sd0 = 2 * tid, s = sd0 >> 7, d0 = sd0 & 127;

    int bs[4], ks[4];
    bool val[4];
#pragma unroll
    for (int row = 0; row < 4; ++row) {
        int r = r0 + row;
        val[row] = (r < R);
        int rr = val[row] ? r : 0;
        int b = rr / nm, mm = rr % nm;
        bs[row] = b;
        ks[row] = l * l + mm;
    }
    float2 a0[4], a1[4];
#pragma unroll
    for (int row = 0; row < 4; ++row) { a0[row] = make_float2(0.f, 0.f); a1[row] = make_float2(0.f, 0.f); }

    for (int i = 0; i < 2; ++i) {
        size_t kb = ((((size_t)l * 2 + i) * 3 + s) * 64) * 128 + d0;
        size_t cb0 = ((size_t)bs[0] * 256 + ks[0]) * 128 + i * 64;
        size_t cb1 = ((size_t)bs[1] * 256 + ks[1]) * 128 + i * 64;
        size_t cb2 = ((size_t)bs[2] * 256 + ks[2]) * 128 + i * 64;
        size_t cb3 = ((size_t)bs[3] * 256 + ks[3]) * 128 + i * 64;
#pragma unroll 4
        for (int u = 0; u < 64; ++u) {
            float2 wr = *(const float2*)&kr[kb + (size_t)u * 128];
            float2 wi = *(const float2*)&ki[kb + (size_t)u * 128];
            float2 c0 = coeffs[cb0 + u];  // block-uniform -> s_load
            float2 c1 = coeffs[cb1 + u];
            float2 c2 = coeffs[cb2 + u];
            float2 c3 = coeffs[cb3 + u];
            a0[0].x += c0.x * wr.x - c0.y * wi.x; a0[0].y += c0.x * wi.x + c0.y * wr.x;
            a1[0].x += c0.x * wr.y - c0.y * wi.y; a1[0].y += c0.x * wi.y + c0.y * wr.y;
            a0[1].x += c1.x * wr.x - c1.y * wi.x; a0[1].y += c1.x * wi.x + c1.y * wr.x;
            a1[1].x += c1.x * wr.y - c1.y * wi.y; a1[1].y += c1.x * wi.y + c1.y * wr.y;
            a0[2].x += c2.x * wr.x - c2.y * wi.x; a0[2].y += c2.x * wi.x + c2.y * wr.x;
            a1[2].x += c2.x * wr.y - c2.y * wi.y; a1[2].y += c2.x * wi.y + c2.y * wr.y;
            a0[3].x += c3.x * wr.x - c3.y * wi.x; a0[3].y += c3.x * wi.x + c3.y * wr.x;
            a1[3].x += c3.x * wr.y - c3.y * wi.y; a1[3].y += c3.x * wi.y + c3.y * wr.y;
        }
    }
#pragma unroll
    for (int row = 0; row < 4; ++row) {
        if (val[row]) {
            float4 st = make_float4(a0[row].x, a0[row].y, a1[row].x, a1[row].y);
            *(float4*)&oc[((size_t)bs[row] * 256 + ks[row]) * 384 + sd0] = st;
        }
    }
}

// K4: theta expansion + stats. grid (31, 8) = (mi, b), 384 threads (sd).
// oc column held in registers (read once total); A_out via LDS broadcast.
// Accumulates Parseval stats with device atomics.
__global__ __launch_bounds__(384) void k_theta_out(const float2* __restrict__ oc,
                                                   const float* __restrict__ A_out,
                                                   float2* __restrict__ G,
                                                   float* __restrict__ ssr,
                                                   float* __restrict__ ssi,
                                                   float* __restrict__ ssq) {
    __shared__ float Ao[3][16][32];  // 6KB
    int mi = blockIdx.x, b = blockIdx.y;
    int m = mi - 15;
    int am = m < 0 ? -m : m;
    int tid = threadIdx.x;
    for (int idx = tid; idx < 1536; idx += 384) {
        int s = idx >> 9, j = (idx >> 5) & 15, t = idx & 31;
        float v = 0.f;
        if (j >= am) v = A_out[((size_t)s * 256 + (j * j + j + m)) * 32 + t];
        Ao[s][j][t] = v;
    }
    __syncthreads();
    int s = tid >> 7;
    float2 c[16];
#pragma unroll
    for (int j = 0; j < 16; ++j) {
        c[j] = make_float2(0.f, 0.f);
        if (j >= am) c[j] = oc[((size_t)b * 256 + (j * j + j + m)) * 384 + tid];
    }
    float sq = 0.f, sr = 0.f, si = 0.f;
    for (int t = 0; t < 32; ++t) {
        float fr = 0.f, fi = 0.f;
#pragma unroll
        for (int j = 0; j < 16; ++j) {
            float a = Ao[s][j][t];      // wave-uniform -> broadcast
            fr += a * c[j].x;
            fi += a * c[j].y;
        }
        G[(((size_t)b * 32 + t) * 31 + mi) * 384 + tid] = make_float2(fr, fi);
        sq += fr * fr + fi * fi;
        if (mi == 15) { sr += fr; si += fi; }
    }
    atomicAdd(&ssq[tid], sq);
    if (mi == 15) {
        atomicAdd(&ssr[tid], sr);
        atomicAdd(&ssi[tid], si);
    }
}

// K5: phi synthesis + BN + gate, fused. grid 256 (bt), 384 threads (sd).
// G column in 62 VGPRs (read once); twiddles block-uniform -> scalar loads.
// mean = ssr/256 (only m=0 survives sum over p); E|y|^2 = ssq/256 (Parseval).
__global__ __launch_bounds__(384) void k_synth_final(const float2* __restrict__ G,
                                                     const float2* __restrict__ tw_out,
                                                     const float* __restrict__ ssr,
                                                     const float* __restrict__ ssi,
                                                     const float* __restrict__ ssq,
                                                     const float* __restrict__ gamma,
                                                     const float* __restrict__ betar,
                                                     const float* __restrict__ betai,
                                                     const float* __restrict__ bias,
                                                     float* __restrict__ out) {
    int bt = blockIdx.x;
    int sd = threadIdx.x, s = sd >> 7;
    float2 g[31];
#pragma unroll
    for (int mi = 0; mi < 31; ++mi)
        g[mi] = G[((size_t)bt * 31 + mi) * 384 + sd];

    const float invN = 1.0f / 256.0f;
    float mur = 0.f, mui = 0.f;
    if (s == 0) { mur = ssr[sd] * invN; mui = ssi[sd] * invN; }
    float var = ssq[sd] * invN - (mur * mur + mui * mui);
    float scale = gamma[sd] / sqrtf(var + 1e-5f);
    float br = (s == 0) ? betar[sd] : 0.f;
    float bi = (s == 0) ? betai[sd] : 0.f;
    float bb = bias[sd];

    for (int p = 0; p < 32; ++p) {
        float fr = 0.f, fi = 0.f;
#pragma unroll
        for (int mi = 0; mi < 31; ++mi) {
            float2 w = tw_out[mi * 32 + p];  // block-uniform -> s_load
            fr += g[mi].x * w.x - g[mi].y * w.y;
            fi += g[mi].x * w.y + g[mi].y * w.x;
        }
        float yr = (fr - mur) * scale + br;
        float yi = (fi - mui) * scale + bi;
        float mag = sqrtf(yr * yr + yi * yi);
        float f = fmaxf(mag + bb, 0.f) / (mag + 1e-6f);
        out[((size_t)bt * 32 + p) * 384 + sd] = yr * f;
    }
}

extern "C" void kernel_launch(void* const* d_in, const int* in_sizes, int n_in,
                              void* d_out, int out_size, void* d_ws, size_t ws_size,
                              hipStream_t stream) {
    const float* xr    = (const float*)d_in[0];
    const float* xi    = (const float*)d_in[1];
    const float* kr    = (const float*)d_in[2];
    const float* ki    = (const float*)d_in[3];
    const float* gamma = (const float*)d_in[4];
    const float* betar = (const float*)d_in[5];
    const float* betai = (const float*)d_in[6];
    const float* bias  = (const float*)d_in[7];
    float* out = (float*)d_out;

    char* ws = (char*)d_ws;
    float2* tw_in  = (float2*)(ws + OFF_TW_IN);
    float2* tw_out = (float2*)(ws + OFF_TW_OUT);
    float*  A_in   = (float*)(ws + OFF_A_IN);
    float*  A_out  = (float*)(ws + OFF_A_OUT);
    float*  stats  = (float*)(ws + OFF_STATS);
    float*  ssr    = stats;
    float*  ssi    = stats + 384;
    float*  ssq    = stats + 768;
    float2* F      = (float2*)(ws + OFF_R1);  // then oc
    float2* oc     = (float2*)(ws + OFF_R1);
    float2* coeffs = (float2*)(ws + OFF_R2);  // then G
    float2* G      = (float2*)(ws + OFF_R2);

    k_tables<<<241, 256, 0, stream>>>(tw_in, tw_out, A_in, A_out, stats);
    k_phi_in<<<512, 256, 0, stream>>>(xr, xi, tw_in, F);
    k_theta_in<<<dim3(31, 8, 2), 128, 0, stream>>>(F, A_in, coeffs);
    k_mix<<<dim3(16, 62), 192, 0, stream>>>(coeffs, kr, ki, oc);
    k_theta_out<<<dim3(31, 8), 384, 0, stream>>>(oc, A_out, G, ssr, ssi, ssq);
    k_synth_final<<<256, 384, 0, stream>>>(G, tw_out, ssr, ssi, ssq,
                                           gamma, betar, betai, bias, out);
}

// Round 7
// 269.389 us; speedup vs baseline: 1.4820x; 1.4820x over previous
//
#include <hip/hip_runtime.h>
#include <math.h>

// SpinSphericalBlock: separable spin-weighted SHT -> channel mix -> inverse SHT
// -> complex BN (spin0 mean, via Parseval on G) -> magnitude-ReLU gating.
//
// Constants: B=8, RES=64, RES_OUT=32, L=15, SPINS_IN=(0,1), SPINS_OUT=(0,1,2),
// C_IN=64, C_OUT=128, NM=31. Output: out_size=3,145,728 float32 = Re(y),
// (b,t,p,s,d) row-major (established R0-R4).
//
// R7: twiddles NEVER loaded from memory in inner loops (R6 post-mortem:
// per-iteration "uniform" VMEM loads are full-latency vector loads; k_phi_in
// was 170us latency-bound at 11% VALUBusy). Twiddle = register rotation.
//
//   K0 k_tables:     Wigner tables (fp64) + zero stats accumulators
//   K1 k_phi_in:     F[bt,m,iu]    = sum_p x[bt,p,iu] e^{-im phi_p}   (rotation)
//   K2 k_theta_in:   coeffs[b,k,iu]= sum_t A_in[i,k,t] F[b,t,m(k),iu]
//   K3 k_mix:        oc[b,k,sd]    = sum_iu coeffs * kernel[l(k),i,s,u,d]
//   K4 k_theta_out:  G[bt,m,sd]    = sum_l A_out[s,k,t] oc[b,k,sd]
//                    + atomic stats (DFT orthogonality/Parseval:
//                      mean = ssr/256, E|y|^2 = ssq/256)
//   K5 k_synth_final: y = BN(sum_m G e^{+im phi'_p}) -> gate -> Re(y) (rotation)

#define PI_D 3.14159265358979323846

// ---------------- workspace layout (bytes) ----------------
#define OFF_A_IN    ((size_t)24320)     // 2*256*64 float    = 131072
#define OFF_A_OUT   ((size_t)155648)    // 3*256*32 float    = 98304
#define OFF_STATS   ((size_t)254208)    // 3*384 float       = 4608
#define OFF_R1      ((size_t)260608)    // F (16.25MB) then oc (6.3MB)
#define OFF_R2      ((size_t)25426688)  // coeffs (2.1MB) then G (24.4MB)
// total ~49.8 MB (known good from R5/R6)

__device__ inline int isqrt_k(int k) {
    int l = (int)sqrtf((float)k + 0.5f);
    while (l * l > k) --l;
    while ((l + 1) * (l + 1) <= k) ++l;
    return l;
}

// d^l_{m,n}(theta), exact factorial-sum formula, double precision.
__device__ double wigner_d_dev(int l, int m, int n, double theta, const double* lf) {
    int an = n < 0 ? -n : n;
    int am = m < 0 ? -m : m;
    if (l < an || l < am) return 0.0;
    double cb = cos(0.5 * theta), sb = sin(0.5 * theta);
    double pref = 0.5 * (lf[l + m] + lf[l - m] + lf[l + n] + lf[l - n]);
    int kmin = max(0, n - m), kmax = min(l + n, l - m);
    if (kmax < kmin) return 0.0;
    double p = pow(cb, (double)(2 * l + n - m - 2 * kmin)) * pow(sb, (double)(m - n + 2 * kmin));
    double r = (sb * sb) / (cb * cb);
    double acc = 0.0;
    for (int k = kmin; k <= kmax; ++k) {
        double lg = pref - (lf[l + n - k] + lf[k] + lf[m - n + k] + lf[l - m - k]);
        double term = exp(lg) * p;
        acc += ((m - n + k) & 1) ? -term : term;
        p *= r;
    }
    return acc;
}

// K0: Wigner tables + zero stats. ranges: A_in 32768 | A_out 24576 | stats 1152
__global__ __launch_bounds__(256) void k_tables(float* __restrict__ A_in,
                                                float* __restrict__ A_out,
                                                float* __restrict__ stats) {
    __shared__ double lf[40];
    if (threadIdx.x == 0) {
        lf[0] = 0.0;
        for (int j = 1; j < 40; ++j) lf[j] = lf[j - 1] + log((double)j);
    }
    __syncthreads();
    int idx = blockIdx.x * 256 + threadIdx.x;
    if (idx < 32768) { // A_in[i][k][t] = (-1)^m norm_l w_t d^l_{m,-s_i}(theta_t)
        int t = idx & 63, k = (idx >> 6) & 255, i = idx >> 14;
        int l = isqrt_k(k);
        int m = k - l * l - l;
        int n = -i;
        double theta = ((double)t + 0.5) * PI_D / 64.0;
        double w = sin(theta) * (PI_D / 64.0) * (2.0 * PI_D / 64.0);
        double norm = sqrt((2.0 * l + 1.0) / (4.0 * PI_D));
        double d = wigner_d_dev(l, m, n, theta, lf);
        A_in[idx] = (float)(((m & 1) ? -1.0 : 1.0) * norm * w * d);
        return;
    }
    idx -= 32768;
    if (idx < 24576) { // A_out[s][k][t] = (-1)^m norm_l d^l_{m,-s}(theta'_t)
        int t = idx & 31, k = (idx >> 5) & 255, s = idx >> 13;
        int l = isqrt_k(k);
        int m = k - l * l - l;
        int n = -s;
        double theta = ((double)t + 0.5) * PI_D / 32.0;
        double norm = sqrt((2.0 * l + 1.0) / (4.0 * PI_D));
        double d = wigner_d_dev(l, m, n, theta, lf);
        A_out[idx] = (float)(((m & 1) ? -1.0 : 1.0) * norm * d);
        return;
    }
    idx -= 24576;
    if (idx < 1152) stats[idx] = 0.f;  // ssr[384] | ssi[384] | ssq[384]
}

// K1: partial phi-DFT via register rotation. grid 512 (bt), 512 threads
// (iu 0..127, mh 0..3; 8 m per thread). Inner loop: 2 coalesced VMEM + 64 FMA,
// NO twiddle loads (w *= step per p; fp32 drift ~1e-6 over 64 steps).
__global__ __launch_bounds__(512) void k_phi_in(const float* __restrict__ xr,
                                                const float* __restrict__ xi,
                                                float2* __restrict__ F) {
    int bt = blockIdx.x;
    int iu = threadIdx.x & 127, mh = threadIdx.x >> 7;
    int mi0 = mh * 8;
    float2 acc[8], w[8], st[8];
#pragma unroll
    for (int j = 0; j < 8; ++j) {
        int m = mi0 + j - 15;
        float sy, sx;
        __sincosf(-(float)m * (float)(PI_D / 32.0), &sy, &sx);
        st[j] = make_float2(sx, sy);
        w[j] = make_float2(1.f, 0.f);
        acc[j] = make_float2(0.f, 0.f);
    }
    const float* xrb = xr + (size_t)bt * 8192 + iu;
    const float* xib = xi + (size_t)bt * 8192 + iu;
    for (int p = 0; p < 64; ++p) {
        float a = xrb[(size_t)p * 128];
        float b = xib[(size_t)p * 128];
#pragma unroll
        for (int j = 0; j < 8; ++j) {
            acc[j].x += a * w[j].x - b * w[j].y;
            acc[j].y += a * w[j].y + b * w[j].x;
            float nx = w[j].x * st[j].x - w[j].y * st[j].y;
            w[j].y = w[j].x * st[j].y + w[j].y * st[j].x;
            w[j].x = nx;
        }
    }
    float2* Fb = F + (size_t)bt * 31 * 128 + iu;
#pragma unroll
    for (int j = 0; j < 8; ++j) {
        int mi = mi0 + j;
        if (mi < 31) Fb[(size_t)mi * 128] = acc[j];
    }
}

// K2: theta contraction. grid (31, 8, 2) = (mi, b, parity), 128 threads (iu).
// Stages A_in rows for l = par+2j (zero-filled below |m|) in LDS; F read once.
__global__ __launch_bounds__(128) void k_theta_in(const float2* __restrict__ F,
                                                  const float* __restrict__ A_in,
                                                  float2* __restrict__ coeffs) {
    __shared__ float lds_A[2][8][64];  // 4KB
    int mi = blockIdx.x, b = blockIdx.y, par = blockIdx.z;
    int m = mi - 15;
    int am = m < 0 ? -m : m;
    int tid = threadIdx.x;
    for (int idx = tid; idx < 1024; idx += 128) {
        int i = idx >> 9, j = (idx >> 6) & 7, t = idx & 63;
        int l = par + 2 * j;
        float v = 0.f;
        if (l >= am) v = A_in[((size_t)i * 256 + (l * l + l + m)) * 64 + t];
        lds_A[i][j][t] = v;
    }
    __syncthreads();
    int iu = tid, i = iu >> 6;
    float2 acc[8];
#pragma unroll
    for (int j = 0; j < 8; ++j) acc[j] = make_float2(0.f, 0.f);
    const float2* Fb = F + ((size_t)b * 64 * 31 + mi) * 128 + iu;
    for (int t = 0; t < 64; ++t) {
        float2 f = Fb[(size_t)t * 31 * 128];
#pragma unroll
        for (int j = 0; j < 8; ++j) {
            float a = lds_A[i][j][t];
            acc[j].x += a * f.x;
            acc[j].y += a * f.y;
        }
    }
#pragma unroll
    for (int j = 0; j < 8; ++j) {
        int l = par + 2 * j;
        if (l >= am)
            coeffs[((size_t)b * 256 + (l * l + l + m)) * 128 + iu] = acc[j];
    }
}

// K3: channel mix. grid (16 l, 62 row-tiles), 192 threads (d-pairs).
// Thread computes 4 rows x 2 sd. coeffs via block-uniform (scalar) loads,
// kernel via float2 vector loads.
__global__ __launch_bounds__(192) void k_mix(const float2* __restrict__ coeffs,
                                             const float* __restrict__ kr,
                                             const float* __restrict__ ki,
                                             float2* __restrict__ oc) {
    int l = blockIdx.x;
    int nm = 2 * l + 1;
    int R = 8 * nm;
    int r0 = blockIdx.y * 4;
    if (r0 >= R) return;
    int tid = threadIdx.x;
    int sd0 = 2 * tid, s = sd0 >> 7, d0 = sd0 & 127;

    int bs[4], ks[4];
    bool val[4];
#pragma unroll
    for (int row = 0; row < 4; ++row) {
        int r = r0 + row;
        val[row] = (r < R);
        int rr = val[row] ? r : 0;
        int b = rr / nm, mm = rr % nm;
        bs[row] = b;
        ks[row] = l * l + mm;
    }
    float2 a0[4], a1[4];
#pragma unroll
    for (int row = 0; row < 4; ++row) { a0[row] = make_float2(0.f, 0.f); a1[row] = make_float2(0.f, 0.f); }

    for (int i = 0; i < 2; ++i) {
        size_t kb = ((((size_t)l * 2 + i) * 3 + s) * 64) * 128 + d0;
        size_t cb0 = ((size_t)bs[0] * 256 + ks[0]) * 128 + i * 64;
        size_t cb1 = ((size_t)bs[1] * 256 + ks[1]) * 128 + i * 64;
        size_t cb2 = ((size_t)bs[2] * 256 + ks[2]) * 128 + i * 64;
        size_t cb3 = ((size_t)bs[3] * 256 + ks[3]) * 128 + i * 64;
#pragma unroll 4
        for (int u = 0; u < 64; ++u) {
            float2 wr = *(const float2*)&kr[kb + (size_t)u * 128];
            float2 wi = *(const float2*)&ki[kb + (size_t)u * 128];
            float2 c0 = coeffs[cb0 + u];
            float2 c1 = coeffs[cb1 + u];
            float2 c2 = coeffs[cb2 + u];
            float2 c3 = coeffs[cb3 + u];
            a0[0].x += c0.x * wr.x - c0.y * wi.x; a0[0].y += c0.x * wi.x + c0.y * wr.x;
            a1[0].x += c0.x * wr.y - c0.y * wi.y; a1[0].y += c0.x * wi.y + c0.y * wr.y;
            a0[1].x += c1.x * wr.x - c1.y * wi.x; a0[1].y += c1.x * wi.x + c1.y * wr.x;
            a1[1].x += c1.x * wr.y - c1.y * wi.y; a1[1].y += c1.x * wi.y + c1.y * wr.y;
            a0[2].x += c2.x * wr.x - c2.y * wi.x; a0[2].y += c2.x * wi.x + c2.y * wr.x;
            a1[2].x += c2.x * wr.y - c2.y * wi.y; a1[2].y += c2.x * wi.y + c2.y * wr.y;
            a0[3].x += c3.x * wr.x - c3.y * wi.x; a0[3].y += c3.x * wi.x + c3.y * wr.x;
            a1[3].x += c3.x * wr.y - c3.y * wi.y; a1[3].y += c3.x * wi.y + c3.y * wr.y;
        }
    }
#pragma unroll
    for (int row = 0; row < 4; ++row) {
        if (val[row]) {
            float4 stv = make_float4(a0[row].x, a0[row].y, a1[row].x, a1[row].y);
            *(float4*)&oc[((size_t)bs[row] * 256 + ks[row]) * 384 + sd0] = stv;
        }
    }
}

// K4: theta expansion + stats. grid (31, 8) = (mi, b), 384 threads (sd).
// oc column held in registers (read once total); A_out via LDS broadcast.
__global__ __launch_bounds__(384) void k_theta_out(const float2* __restrict__ oc,
                                                   const float* __restrict__ A_out,
                                                   float2* __restrict__ G,
                                                   float* __restrict__ ssr,
                                                   float* __restrict__ ssi,
                                                   float* __restrict__ ssq) {
    __shared__ float Ao[3][16][32];  // 6KB
    int mi = blockIdx.x, b = blockIdx.y;
    int m = mi - 15;
    int am = m < 0 ? -m : m;
    int tid = threadIdx.x;
    for (int idx = tid; idx < 1536; idx += 384) {
        int s = idx >> 9, j = (idx >> 5) & 15, t = idx & 31;
        float v = 0.f;
        if (j >= am) v = A_out[((size_t)s * 256 + (j * j + j + m)) * 32 + t];
        Ao[s][j][t] = v;
    }
    __syncthreads();
    int s = tid >> 7;
    float2 c[16];
#pragma unroll
    for (int j = 0; j < 16; ++j) {
        c[j] = make_float2(0.f, 0.f);
        if (j >= am) c[j] = oc[((size_t)b * 256 + (j * j + j + m)) * 384 + tid];
    }
    float sq = 0.f, sr = 0.f, si = 0.f;
    for (int t = 0; t < 32; ++t) {
        float fr = 0.f, fi = 0.f;
#pragma unroll
        for (int j = 0; j < 16; ++j) {
            float a = Ao[s][j][t];
            fr += a * c[j].x;
            fi += a * c[j].y;
        }
        G[(((size_t)b * 32 + t) * 31 + mi) * 384 + tid] = make_float2(fr, fi);
        sq += fr * fr + fi * fi;
        if (mi == 15) { sr += fr; si += fi; }
    }
    atomicAdd(&ssq[tid], sq);
    if (mi == 15) {
        atomicAdd(&ssr[tid], sr);
        atomicAdd(&ssi[tid], si);
    }
}

// K5: phi synthesis + BN + gate, fused, twiddle-by-rotation. grid 256 (bt),
// 384 threads (sd). G column in registers (read once); per p: 62 adds for the
// DFT value at phi_p, then rotate all 31 g by e^{+im*2pi/32}. Zero inner loads.
__global__ __launch_bounds__(384) void k_synth_final(const float2* __restrict__ G,
                                                     const float* __restrict__ ssr,
                                                     const float* __restrict__ ssi,
                                                     const float* __restrict__ ssq,
                                                     const float* __restrict__ gamma,
                                                     const float* __restrict__ betar,
                                                     const float* __restrict__ betai,
                                                     const float* __restrict__ bias,
                                                     float* __restrict__ out) {
    int bt = blockIdx.x;
    int sd = threadIdx.x, s = sd >> 7;
    float2 g[31], st[31];
#pragma unroll
    for (int mi = 0; mi < 31; ++mi) {
        g[mi] = G[((size_t)bt * 31 + mi) * 384 + sd];
        float sy, sx;
        __sincosf((float)(mi - 15) * (float)(PI_D / 16.0), &sy, &sx);
        st[mi] = make_float2(sx, sy);
    }

    const float invN = 1.0f / 256.0f;
    float mur = 0.f, mui = 0.f;
    if (s == 0) { mur = ssr[sd] * invN; mui = ssi[sd] * invN; }
    float var = ssq[sd] * invN - (mur * mur + mui * mui);
    float scale = gamma[sd] / sqrtf(var + 1e-5f);
    float br = (s == 0) ? betar[sd] : 0.f;
    float bi = (s == 0) ? betai[sd] : 0.f;
    float bb = bias[sd];

    for (int p = 0; p < 32; ++p) {
        float fr = 0.f, fi = 0.f;
#pragma unroll
        for (int mi = 0; mi < 31; ++mi) {
            fr += g[mi].x;
            fi += g[mi].y;
        }
        float yr = (fr - mur) * scale + br;
        float yi = (fi - mui) * scale + bi;
        float mag = sqrtf(yr * yr + yi * yi);
        float f = fmaxf(mag + bb, 0.f) / (mag + 1e-6f);
        out[((size_t)bt * 32 + p) * 384 + sd] = yr * f;
#pragma unroll
        for (int mi = 0; mi < 31; ++mi) {
            float nx = g[mi].x * st[mi].x - g[mi].y * st[mi].y;
            g[mi].y = g[mi].x * st[mi].y + g[mi].y * st[mi].x;
            g[mi].x = nx;
        }
    }
}

extern "C" void kernel_launch(void* const* d_in, const int* in_sizes, int n_in,
                              void* d_out, int out_size, void* d_ws, size_t ws_size,
                              hipStream_t stream) {
    const float* xr    = (const float*)d_in[0];
    const float* xi    = (const float*)d_in[1];
    const float* kr    = (const float*)d_in[2];
    const float* ki    = (const float*)d_in[3];
    const float* gamma = (const float*)d_in[4];
    const float* betar = (const float*)d_in[5];
    const float* betai = (const float*)d_in[6];
    const float* bias  = (const float*)d_in[7];
    float* out = (float*)d_out;

    char* ws = (char*)d_ws;
    float*  A_in   = (float*)(ws + OFF_A_IN);
    float*  A_out  = (float*)(ws + OFF_A_OUT);
    float*  stats  = (float*)(ws + OFF_STATS);
    float*  ssr    = stats;
    float*  ssi    = stats + 384;
    float*  ssq    = stats + 768;
    float2* F      = (float2*)(ws + OFF_R1);  // then oc
    float2* oc     = (float2*)(ws + OFF_R1);
    float2* coeffs = (float2*)(ws + OFF_R2);  // then G
    float2* G      = (float2*)(ws + OFF_R2);

    k_tables<<<229, 256, 0, stream>>>(A_in, A_out, stats);
    k_phi_in<<<512, 512, 0, stream>>>(xr, xi, F);
    k_theta_in<<<dim3(31, 8, 2), 128, 0, stream>>>(F, A_in, coeffs);
    k_mix<<<dim3(16, 62), 192, 0, stream>>>(coeffs, kr, ki, oc);
    k_theta_out<<<dim3(31, 8), 384, 0, stream>>>(oc, A_out, G, ssr, ssi, ssq);
    k_synth_final<<<256, 384, 0, stream>>>(G, ssr, ssi, ssq,
                                           gamma, betar, betai, bias, out);
}

// Round 8
// 253.747 us; speedup vs baseline: 1.5734x; 1.0616x over previous
//
#include <hip/hip_runtime.h>
#include <math.h>

// SpinSphericalBlock: separable spin-weighted SHT -> channel mix -> inverse SHT
// -> complex BN (spin0 mean, via Parseval on G) -> magnitude-ReLU gating.
//
// Constants: B=8, RES=64, RES_OUT=32, L=15, SPINS_IN=(0,1), SPINS_OUT=(0,1,2),
// C_IN=64, C_OUT=128, NM=31. Output: out_size=3,145,728 float32 = Re(y),
// (b,t,p,s,d) row-major (established R0-R4).
//
// R8: k_mix k-major (256 equal blocks, LDS-staged coeffs, 8 acc chains);
// k_theta_in 512-thread t-split (1984 waves, F read once). R7 post-mortem:
// both were latency-bound (<18% occupancy, dead blocks, uniform-load serial).
//
//   K0 k_tables:     Wigner tables (fp64) + zero stats accumulators
//   K1 k_phi_in:     F[bt,m,iu]    = sum_p x[bt,p,iu] e^{-im phi_p}   (rotation)
//   K2 k_theta_in:   coeffs[b,k,iu]= sum_t A_in[i,k,t] F[b,t,m(k),iu]
//   K3 k_mix:        oc[b,k,sd]    = sum_iu coeffs * kernel[l(k),i,s,u,d]
//   K4 k_theta_out:  G[bt,m,sd]    = sum_l A_out[s,k,t] oc[b,k,sd]  + stats
//   K5 k_synth_final: y = BN(sum_m G e^{+im phi'_p}) -> gate -> Re(y) (rotation)

#define PI_D 3.14159265358979323846

// ---------------- workspace layout (bytes) ----------------
#define OFF_A_IN    ((size_t)24320)     // 2*256*64 float    = 131072
#define OFF_A_OUT   ((size_t)155648)    // 3*256*32 float    = 98304
#define OFF_STATS   ((size_t)254208)    // 3*384 float       = 4608
#define OFF_R1      ((size_t)260608)    // F (16.25MB) then oc (6.3MB)
#define OFF_R2      ((size_t)25426688)  // coeffs (2.1MB) then G (24.4MB)

__device__ inline int isqrt_k(int k) {
    int l = (int)sqrtf((float)k + 0.5f);
    while (l * l > k) --l;
    while ((l + 1) * (l + 1) <= k) ++l;
    return l;
}

// d^l_{m,n}(theta), exact factorial-sum formula, double precision.
__device__ double wigner_d_dev(int l, int m, int n, double theta, const double* lf) {
    int an = n < 0 ? -n : n;
    int am = m < 0 ? -m : m;
    if (l < an || l < am) return 0.0;
    double cb = cos(0.5 * theta), sb = sin(0.5 * theta);
    double pref = 0.5 * (lf[l + m] + lf[l - m] + lf[l + n] + lf[l - n]);
    int kmin = max(0, n - m), kmax = min(l + n, l - m);
    if (kmax < kmin) return 0.0;
    double p = pow(cb, (double)(2 * l + n - m - 2 * kmin)) * pow(sb, (double)(m - n + 2 * kmin));
    double r = (sb * sb) / (cb * cb);
    double acc = 0.0;
    for (int k = kmin; k <= kmax; ++k) {
        double lg = pref - (lf[l + n - k] + lf[k] + lf[m - n + k] + lf[l - m - k]);
        double term = exp(lg) * p;
        acc += ((m - n + k) & 1) ? -term : term;
        p *= r;
    }
    return acc;
}

// K0: Wigner tables + zero stats. ranges: A_in 32768 | A_out 24576 | stats 1152
__global__ __launch_bounds__(256) void k_tables(float* __restrict__ A_in,
                                                float* __restrict__ A_out,
                                                float* __restrict__ stats) {
    __shared__ double lf[40];
    if (threadIdx.x == 0) {
        lf[0] = 0.0;
        for (int j = 1; j < 40; ++j) lf[j] = lf[j - 1] + log((double)j);
    }
    __syncthreads();
    int idx = blockIdx.x * 256 + threadIdx.x;
    if (idx < 32768) {
        int t = idx & 63, k = (idx >> 6) & 255, i = idx >> 14;
        int l = isqrt_k(k);
        int m = k - l * l - l;
        int n = -i;
        double theta = ((double)t + 0.5) * PI_D / 64.0;
        double w = sin(theta) * (PI_D / 64.0) * (2.0 * PI_D / 64.0);
        double norm = sqrt((2.0 * l + 1.0) / (4.0 * PI_D));
        double d = wigner_d_dev(l, m, n, theta, lf);
        A_in[idx] = (float)(((m & 1) ? -1.0 : 1.0) * norm * w * d);
        return;
    }
    idx -= 32768;
    if (idx < 24576) {
        int t = idx & 31, k = (idx >> 5) & 255, s = idx >> 13;
        int l = isqrt_k(k);
        int m = k - l * l - l;
        int n = -s;
        double theta = ((double)t + 0.5) * PI_D / 32.0;
        double norm = sqrt((2.0 * l + 1.0) / (4.0 * PI_D));
        double d = wigner_d_dev(l, m, n, theta, lf);
        A_out[idx] = (float)(((m & 1) ? -1.0 : 1.0) * norm * d);
        return;
    }
    idx -= 24576;
    if (idx < 1152) stats[idx] = 0.f;
}

// K1: partial phi-DFT via register rotation (unchanged from R7).
__global__ __launch_bounds__(512) void k_phi_in(const float* __restrict__ xr,
                                                const float* __restrict__ xi,
                                                float2* __restrict__ F) {
    int bt = blockIdx.x;
    int iu = threadIdx.x & 127, mh = threadIdx.x >> 7;
    int mi0 = mh * 8;
    float2 acc[8], w[8], st[8];
#pragma unroll
    for (int j = 0; j < 8; ++j) {
        int m = mi0 + j - 15;
        float sy, sx;
        __sincosf(-(float)m * (float)(PI_D / 32.0), &sy, &sx);
        st[j] = make_float2(sx, sy);
        w[j] = make_float2(1.f, 0.f);
        acc[j] = make_float2(0.f, 0.f);
    }
    const float* xrb = xr + (size_t)bt * 8192 + iu;
    const float* xib = xi + (size_t)bt * 8192 + iu;
    for (int p = 0; p < 64; ++p) {
        float a = xrb[(size_t)p * 128];
        float b = xib[(size_t)p * 128];
#pragma unroll
        for (int j = 0; j < 8; ++j) {
            acc[j].x += a * w[j].x - b * w[j].y;
            acc[j].y += a * w[j].y + b * w[j].x;
            float nx = w[j].x * st[j].x - w[j].y * st[j].y;
            w[j].y = w[j].x * st[j].y + w[j].y * st[j].x;
            w[j].x = nx;
        }
    }
    float2* Fb = F + (size_t)bt * 31 * 128 + iu;
#pragma unroll
    for (int j = 0; j < 8; ++j) {
        int mi = mi0 + j;
        if (mi < 31) Fb[(size_t)mi * 128] = acc[j];
    }
}

// K2: theta contraction. grid (31, 8) = (mi, b), 512 threads (iu, th=t-quarter).
// All 16 l (both parities) per thread; F read ONCE; LDS tree-reduce over th.
__global__ __launch_bounds__(512) void k_theta_in(const float2* __restrict__ F,
                                                  const float* __restrict__ A_in,
                                                  float2* __restrict__ coeffs) {
    __shared__ float A[2][16][64];      // 8 KB, zero-padded below |m|
    __shared__ float2 red[2][16][128];  // 32 KB reduction buffer
    int mi = blockIdx.x, b = blockIdx.y;
    int m = mi - 15;
    int am = m < 0 ? -m : m;
    int tid = threadIdx.x;
    for (int idx = tid; idx < 2048; idx += 512) {
        int i = idx >> 10, j = (idx >> 6) & 15, t = idx & 63;
        float v = 0.f;
        if (j >= am) v = A_in[((size_t)i * 256 + (j * j + j + m)) * 64 + t];
        A[i][j][t] = v;
    }
    __syncthreads();
    int iu = tid & 127, th = tid >> 7, i = iu >> 6;
    float2 acc[16];
#pragma unroll
    for (int j = 0; j < 16; ++j) acc[j] = make_float2(0.f, 0.f);
    const float2* Fb = F + ((size_t)b * 64 * 31 + mi) * 128 + iu;
    for (int tt = 0; tt < 16; ++tt) {
        int t = th * 16 + tt;
        float2 f = Fb[(size_t)t * 31 * 128];
#pragma unroll
        for (int j = 0; j < 16; ++j) {
            float a = A[i][j][t];   // wave-uniform -> broadcast
            acc[j].x += a * f.x;
            acc[j].y += a * f.y;
        }
    }
    if (th >= 2) {
#pragma unroll
        for (int j = 0; j < 16; ++j) red[th - 2][j][iu] = acc[j];
    }
    __syncthreads();
    if (th < 2) {
#pragma unroll
        for (int j = 0; j < 16; ++j) {
            float2 r = red[th][j][iu];
            acc[j].x += r.x;
            acc[j].y += r.y;
        }
    }
    __syncthreads();
    if (th == 1) {
#pragma unroll
        for (int j = 0; j < 16; ++j) red[0][j][iu] = acc[j];
    }
    __syncthreads();
    if (th == 0) {
#pragma unroll
        for (int j = 0; j < 16; ++j) {
            if (j >= am) {
                float2 r = red[0][j][iu];
                coeffs[((size_t)b * 256 + (j * j + j + m)) * 128 + iu] =
                    make_float2(acc[j].x + r.x, acc[j].y + r.y);
            }
        }
    }
}

// K3: channel mix, k-major. grid 256 (k), 384 threads (sd).
// All 8 b coeffs rows staged in LDS as c[iu][b] (broadcast ds_read_b128-able);
// inner u-loop: 2 coalesced 4B kernel loads + 8 independent complex FMAs.
__global__ __launch_bounds__(384) void k_mix(const float2* __restrict__ coeffs,
                                             const float* __restrict__ kr,
                                             const float* __restrict__ ki,
                                             float2* __restrict__ oc) {
    __shared__ float2 c[128][8];  // [iu][b], 8 KB
    int k = blockIdx.x;
    int l = isqrt_k(k);
    int tid = threadIdx.x;
    for (int idx = tid; idx < 1024; idx += 384) {
        int b = idx >> 7, iu = idx & 127;
        c[iu][b] = coeffs[((size_t)b * 256 + k) * 128 + iu];
    }
    __syncthreads();
    int sd = tid, s = sd >> 7, d = sd & 127;
    float2 acc[8];
#pragma unroll
    for (int b = 0; b < 8; ++b) acc[b] = make_float2(0.f, 0.f);
    size_t base = ((size_t)(6 * l + s) * 64) * 128 + d;  // ((2l+i)*3+s) with i=0
    for (int i = 0; i < 2; ++i) {
        const float* krp = kr + base + (size_t)i * 3 * 8192;
        const float* kip = ki + base + (size_t)i * 3 * 8192;
#pragma unroll 8
        for (int u = 0; u < 64; ++u) {
            float wr = krp[(size_t)u * 128];
            float wi = kip[(size_t)u * 128];
            int iu = i * 64 + u;
#pragma unroll
            for (int b = 0; b < 8; ++b) {
                float2 cv = c[iu][b];
                acc[b].x += cv.x * wr - cv.y * wi;
                acc[b].y += cv.x * wi + cv.y * wr;
            }
        }
    }
#pragma unroll
    for (int b = 0; b < 8; ++b)
        oc[((size_t)b * 256 + k) * 384 + sd] = acc[b];
}

// K4: theta expansion + stats (unchanged from R7). grid (31, 8), 384 threads.
__global__ __launch_bounds__(384) void k_theta_out(const float2* __restrict__ oc,
                                                   const float* __restrict__ A_out,
                                                   float2* __restrict__ G,
                                                   float* __restrict__ ssr,
                                                   float* __restrict__ ssi,
                                                   float* __restrict__ ssq) {
    __shared__ float Ao[3][16][32];  // 6KB
    int mi = blockIdx.x, b = blockIdx.y;
    int m = mi - 15;
    int am = m < 0 ? -m : m;
    int tid = threadIdx.x;
    for (int idx = tid; idx < 1536; idx += 384) {
        int s = idx >> 9, j = (idx >> 5) & 15, t = idx & 31;
        float v = 0.f;
        if (j >= am) v = A_out[((size_t)s * 256 + (j * j + j + m)) * 32 + t];
        Ao[s][j][t] = v;
    }
    __syncthreads();
    int s = tid >> 7;
    float2 c[16];
#pragma unroll
    for (int j = 0; j < 16; ++j) {
        c[j] = make_float2(0.f, 0.f);
        if (j >= am) c[j] = oc[((size_t)b * 256 + (j * j + j + m)) * 384 + tid];
    }
    float sq = 0.f, sr = 0.f, si = 0.f;
    for (int t = 0; t < 32; ++t) {
        float fr = 0.f, fi = 0.f;
#pragma unroll
        for (int j = 0; j < 16; ++j) {
            float a = Ao[s][j][t];
            fr += a * c[j].x;
            fi += a * c[j].y;
        }
        G[(((size_t)b * 32 + t) * 31 + mi) * 384 + tid] = make_float2(fr, fi);
        sq += fr * fr + fi * fi;
        if (mi == 15) { sr += fr; si += fi; }
    }
    atomicAdd(&ssq[tid], sq);
    if (mi == 15) {
        atomicAdd(&ssr[tid], sr);
        atomicAdd(&ssi[tid], si);
    }
}

// K5: phi synthesis + BN + gate, twiddle-by-rotation (unchanged from R7).
__global__ __launch_bounds__(384) void k_synth_final(const float2* __restrict__ G,
                                                     const float* __restrict__ ssr,
                                                     const float* __restrict__ ssi,
                                                     const float* __restrict__ ssq,
                                                     const float* __restrict__ gamma,
                                                     const float* __restrict__ betar,
                                                     const float* __restrict__ betai,
                                                     const float* __restrict__ bias,
                                                     float* __restrict__ out) {
    int bt = blockIdx.x;
    int sd = threadIdx.x, s = sd >> 7;
    float2 g[31], st[31];
#pragma unroll
    for (int mi = 0; mi < 31; ++mi) {
        g[mi] = G[((size_t)bt * 31 + mi) * 384 + sd];
        float sy, sx;
        __sincosf((float)(mi - 15) * (float)(PI_D / 16.0), &sy, &sx);
        st[mi] = make_float2(sx, sy);
    }
    const float invN = 1.0f / 256.0f;
    float mur = 0.f, mui = 0.f;
    if (s == 0) { mur = ssr[sd] * invN; mui = ssi[sd] * invN; }
    float var = ssq[sd] * invN - (mur * mur + mui * mui);
    float scale = gamma[sd] / sqrtf(var + 1e-5f);
    float br = (s == 0) ? betar[sd] : 0.f;
    float bi = (s == 0) ? betai[sd] : 0.f;
    float bb = bias[sd];
    for (int p = 0; p < 32; ++p) {
        float fr = 0.f, fi = 0.f;
#pragma unroll
        for (int mi = 0; mi < 31; ++mi) {
            fr += g[mi].x;
            fi += g[mi].y;
        }
        float yr = (fr - mur) * scale + br;
        float yi = (fi - mui) * scale + bi;
        float mag = sqrtf(yr * yr + yi * yi);
        float f = fmaxf(mag + bb, 0.f) / (mag + 1e-6f);
        out[((size_t)bt * 32 + p) * 384 + sd] = yr * f;
#pragma unroll
        for (int mi = 0; mi < 31; ++mi) {
            float nx = g[mi].x * st[mi].x - g[mi].y * st[mi].y;
            g[mi].y = g[mi].x * st[mi].y + g[mi].y * st[mi].x;
            g[mi].x = nx;
        }
    }
}

extern "C" void kernel_launch(void* const* d_in, const int* in_sizes, int n_in,
                              void* d_out, int out_size, void* d_ws, size_t ws_size,
                              hipStream_t stream) {
    const float* xr    = (const float*)d_in[0];
    const float* xi    = (const float*)d_in[1];
    const float* kr    = (const float*)d_in[2];
    const float* ki    = (const float*)d_in[3];
    const float* gamma = (const float*)d_in[4];
    const float* betar = (const float*)d_in[5];
    const float* betai = (const float*)d_in[6];
    const float* bias  = (const float*)d_in[7];
    float* out = (float*)d_out;

    char* ws = (char*)d_ws;
    float*  A_in   = (float*)(ws + OFF_A_IN);
    float*  A_out  = (float*)(ws + OFF_A_OUT);
    float*  stats  = (float*)(ws + OFF_STATS);
    float*  ssr    = stats;
    float*  ssi    = stats + 384;
    float*  ssq    = stats + 768;
    float2* F      = (float2*)(ws + OFF_R1);  // then oc
    float2* oc     = (float2*)(ws + OFF_R1);
    float2* coeffs = (float2*)(ws + OFF_R2);  // then G
    float2* G      = (float2*)(ws + OFF_R2);

    k_tables<<<229, 256, 0, stream>>>(A_in, A_out, stats);
    k_phi_in<<<512, 512, 0, stream>>>(xr, xi, F);
    k_theta_in<<<dim3(31, 8), 512, 0, stream>>>(F, A_in, coeffs);
    k_mix<<<256, 384, 0, stream>>>(coeffs, kr, ki, oc);
    k_theta_out<<<dim3(31, 8), 384, 0, stream>>>(oc, A_out, G, ssr, ssi, ssq);
    k_synth_final<<<256, 384, 0, stream>>>(G, ssr, ssi, ssq,
                                           gamma, betar, betai, bias, out);
}